// Round 1
// baseline (569.414 us; speedup 1.0000x reference)
//
#include <hip/hip_runtime.h>

typedef unsigned short u16;
typedef unsigned int u32;
using bf16x8  = __attribute__((ext_vector_type(8))) __bf16;
using u16x8   = __attribute__((ext_vector_type(8), may_alias)) u16;
using u16x4   = __attribute__((ext_vector_type(4), may_alias)) u16;
using f32x4   = __attribute__((ext_vector_type(4))) float;
using f32x4_a = __attribute__((ext_vector_type(4), may_alias)) float;

#define DEV __device__ __forceinline__

constexpr int Bn = 4, Hn = 4, Nn = 2048, Mn = 2048, Dn = 64, DIMn = 256;
constexpr float SCALEc = 0.125f;   // 64^-0.5
constexpr float SHIFTc = 12.0f;    // fixed softmax shift (max logit ~6; overflow needs >100)
constexpr int LSTRIDE = 152;       // u16; 76 dwords, 76%32=12 -> conflict-free b64/b128

DEV float bf2f(u16 h) { u32 u = ((u32)h) << 16; return __builtin_bit_cast(float, u); }
DEV u16 f2bf(float f) {
    u32 u = __builtin_bit_cast(u32, f);
    u += 0x7fffu + ((u >> 16) & 1u);   // RNE
    return (u16)(u >> 16);
}
DEV bf16x8 ld8bf(const u16* p) {
    return __builtin_bit_cast(bf16x8, *reinterpret_cast<const u16x8*>(p));
}
DEV bf16x8 ld8f_bf(const float* p) {
    const f32x4 a = *reinterpret_cast<const f32x4_a*>(p);
    const f32x4 b = *reinterpret_cast<const f32x4_a*>(p + 4);
    u16x8 r;
    r[0] = f2bf(a[0]); r[1] = f2bf(a[1]); r[2] = f2bf(a[2]); r[3] = f2bf(a[3]);
    r[4] = f2bf(b[0]); r[5] = f2bf(b[1]); r[6] = f2bf(b[2]); r[7] = f2bf(b[3]);
    return __builtin_bit_cast(bf16x8, r);
}

// ---------------------------------------------------------------------------
// Fused QKV projection (one launch, 1024 blocks, 16-row tiles):
//  blocks [0,512):   Q = x_query @ Wq^T + bq  -> fp32 (B,H,N,D)
//  blocks [512,1024): K -> bf16 (B,H,M,D); V -> bf16 (B,H,D,M) transposed
// ---------------------------------------------------------------------------
__global__ __launch_bounds__(256, 4) void qkv_kernel(
    const float* __restrict__ Xq, const float* __restrict__ Wq, const float* __restrict__ bq,
    const float* __restrict__ Xc, const float* __restrict__ Wk, const float* __restrict__ bk,
    const float* __restrict__ Wv, const float* __restrict__ bv,
    float* __restrict__ Q, u16* __restrict__ K, u16* __restrict__ V)
{
    const int wave = threadIdx.x >> 6, lane = threadIdx.x & 63;
    const int quad = lane >> 4, l16 = lane & 15;
    const int o0 = wave * 64;

    if (blockIdx.x < 512) {
        const int row0 = blockIdx.x * 16;
        const int b = row0 >> 11, n0 = row0 & 2047;
        f32x4 acc[4] = {};
        #pragma unroll
        for (int k0 = 0; k0 < 256; k0 += 32) {
            bf16x8 wf[4];
            const bf16x8 af = ld8f_bf(Xq + (size_t)(row0 + l16) * DIMn + k0 + quad * 8);
            #pragma unroll
            for (int os = 0; os < 4; os++)
                wf[os] = ld8f_bf(Wq + (size_t)(o0 + os * 16 + l16) * DIMn + k0 + quad * 8);
            #pragma unroll
            for (int os = 0; os < 4; os++)
                acc[os] = __builtin_amdgcn_mfma_f32_16x16x32_bf16(af, wf[os], acc[os], 0, 0, 0);
        }
        #pragma unroll
        for (int os = 0; os < 4; os++) {
            const int col = o0 + os * 16 + l16;
            const int h = col >> 6, d = col & 63;
            const float bb = bq[col];
            #pragma unroll
            for (int r = 0; r < 4; r++) {
                const int n = n0 + quad * 4 + r;
                Q[((size_t)(b * Hn + h) * Nn + n) * Dn + d] = acc[os][r] + bb;
            }
        }
    } else {
        const int row0 = (blockIdx.x - 512) * 16;
        const int b = row0 >> 11, n0 = row0 & 2047;
        f32x4 ack[4] = {};
        f32x4 acv[4] = {};
        #pragma unroll
        for (int k0 = 0; k0 < 256; k0 += 32) {
            bf16x8 wkf[4], wvf[4];
            const bf16x8 af = ld8f_bf(Xc + (size_t)(row0 + l16) * DIMn + k0 + quad * 8);
            #pragma unroll
            for (int os = 0; os < 4; os++) {
                wkf[os] = ld8f_bf(Wk + (size_t)(o0 + os * 16 + l16) * DIMn + k0 + quad * 8);
                wvf[os] = ld8f_bf(Wv + (size_t)(o0 + os * 16 + l16) * DIMn + k0 + quad * 8);
            }
            #pragma unroll
            for (int os = 0; os < 4; os++) {
                ack[os] = __builtin_amdgcn_mfma_f32_16x16x32_bf16(af, wkf[os], ack[os], 0, 0, 0);
                acv[os] = __builtin_amdgcn_mfma_f32_16x16x32_bf16(wvf[os], af, acv[os], 0, 0, 0);
            }
        }
        #pragma unroll
        for (int os = 0; os < 4; os++) {
            const int col = o0 + os * 16 + l16;
            const int h = col >> 6, d = col & 63;
            const float bb = bk[col];
            #pragma unroll
            for (int r = 0; r < 4; r++) {
                const int m = n0 + quad * 4 + r;
                K[((size_t)(b * Hn + h) * Mn + m) * Dn + d] = f2bf(ack[os][r] + bb);
            }
        }
        #pragma unroll
        for (int os = 0; os < 4; os++)
            #pragma unroll
            for (int r = 0; r < 4; r++) {
                const int colf = o0 + os * 16 + quad * 4 + r;
                const int h = colf >> 6, d = colf & 63;
                const float bb = bv[colf];
                const int m = n0 + l16;
                V[((size_t)(b * Hn + h) * Dn + d) * Mn + m] = f2bf(acv[os][r] + bb);
            }
    }
}

// ---------------------------------------------------------------------------
// Flash attention, split-M, transposed score tiles (S^T = K Q^T).
// Grid (N/128, H, B*S). Block 256 thr = 4 waves; wave owns 32 Q-rows (2
// n-subtiles) and M-range [split*Mn/S, (split+1)*Mn/S). Every K fragment
// feeds 8 MFMAs, every V fragment 2. Depth-1 software pipeline on K+geo.
// Fixed softmax shift -> split partials directly addable; combine normalizes.
// Single-buffer wave-private LDS (in-order DS pipe), stride 152 -> no
// conflicts. No barriers. __launch_bounds__(256,4): VGPR budget 128.
// ---------------------------------------------------------------------------
__global__ __launch_bounds__(256, 4) void attn_kernel(
    const float* __restrict__ Q,    // (B,H,N,D) fp32
    const u16* __restrict__ K,      // (B,H,M,D) bf16
    const u16* __restrict__ V,      // (B,H,D,M) bf16
    const float* __restrict__ geo,  // (B,H,N,M) fp32
    float* __restrict__ Pnum,       // (S, B*N, 256) fp32 numerator partials
    float* __restrict__ Lsum,       // (S, B, H, N) fp32 denominator partials
    int S)
{
    __shared__ __align__(16) u16 lds[4][32 * LSTRIDE];   // 38912 B -> 4 blocks/CU

    const int h = blockIdx.y;
    const int b = blockIdx.z / S, split = blockIdx.z % S;
    const int wave = threadIdx.x >> 6, lane = threadIdx.x & 63;
    const int quad = lane >> 4, l16 = lane & 15;
    const int nbase = blockIdx.x * 128 + wave * 32;
    const int mlen = Mn / S, mbeg = split * mlen;

    const float* Qh = Q + ((size_t)(b * Hn + h) * Nn + nbase) * Dn;
    const u16*   Kh = K + (size_t)(b * Hn + h) * Mn * Dn;
    const u16*   Vh = V + (size_t)(b * Hn + h) * Dn * Mn;
    const float* Gq0 = geo + ((size_t)(b * Hn + h) * Nn + nbase + l16) * (size_t)Mn + quad * 4;
    const float* Gq1 = Gq0 + (size_t)16 * Mn;

    // Q^T B-fragments (hi/lo split for compensated QK^T), 2 n-subtiles
    bf16x8 qh[2][2], ql[2][2];
    #pragma unroll
    for (int nt = 0; nt < 2; nt++)
        #pragma unroll
        for (int kh = 0; kh < 2; kh++) {
            const float* qp = Qh + (size_t)(nt * 16 + l16) * Dn + kh * 32 + quad * 8;
            const f32x4 a = *reinterpret_cast<const f32x4_a*>(qp);
            const f32x4 c = *reinterpret_cast<const f32x4_a*>(qp + 4);
            u16x8 hi, lo;
            #pragma unroll
            for (int j = 0; j < 4; j++) {
                hi[j] = f2bf(a[j]); lo[j] = f2bf(a[j] - bf2f(hi[j]));
                hi[4 + j] = f2bf(c[j]); lo[4 + j] = f2bf(c[j] - bf2f(hi[4 + j]));
            }
            qh[nt][kh] = __builtin_bit_cast(bf16x8, hi);
            ql[nt][kh] = __builtin_bit_cast(bf16x8, lo);
        }

    f32x4 oacc[2][4] = {};
    float lsum0 = 0.f, lsum1 = 0.f;
    u16* pl = &lds[wave][0];
    const u16* kbase = Kh + (size_t)l16 * Dn + quad * 8;

    for (int m0 = mbeg; m0 < mbeg + mlen; m0 += 128) {
        // --- QK^T + softmax numerator for 32n x 128m, depth-1 pipelined ---
        const u16* kp0 = kbase + (size_t)m0 * Dn;
        bf16x8 kb0 = ld8bf(kp0), kb1 = ld8bf(kp0 + 32);
        f32x4 g0 = *reinterpret_cast<const f32x4_a*>(Gq0 + m0);
        f32x4 g1 = *reinterpret_cast<const f32x4_a*>(Gq1 + m0);
        #pragma unroll
        for (int ms = 0; ms < 8; ms++) {
            bf16x8 nk0, nk1; f32x4 ng0, ng1;
            if (ms < 7) {
                const int mb = m0 + (ms + 1) * 16;
                const u16* kp = kbase + (size_t)mb * Dn;
                nk0 = ld8bf(kp); nk1 = ld8bf(kp + 32);
                ng0 = *reinterpret_cast<const f32x4_a*>(Gq0 + mb);
                ng1 = *reinterpret_cast<const f32x4_a*>(Gq1 + mb);
            }
            f32x4 s0 = {}, s1 = {};
            __builtin_amdgcn_s_setprio(1);
            s0 = __builtin_amdgcn_mfma_f32_16x16x32_bf16(kb0, qh[0][0], s0, 0, 0, 0);
            s1 = __builtin_amdgcn_mfma_f32_16x16x32_bf16(kb0, qh[1][0], s1, 0, 0, 0);
            s0 = __builtin_amdgcn_mfma_f32_16x16x32_bf16(kb0, ql[0][0], s0, 0, 0, 0);
            s1 = __builtin_amdgcn_mfma_f32_16x16x32_bf16(kb0, ql[1][0], s1, 0, 0, 0);
            s0 = __builtin_amdgcn_mfma_f32_16x16x32_bf16(kb1, qh[0][1], s0, 0, 0, 0);
            s1 = __builtin_amdgcn_mfma_f32_16x16x32_bf16(kb1, qh[1][1], s1, 0, 0, 0);
            s0 = __builtin_amdgcn_mfma_f32_16x16x32_bf16(kb1, ql[0][1], s0, 0, 0, 0);
            s1 = __builtin_amdgcn_mfma_f32_16x16x32_bf16(kb1, ql[1][1], s1, 0, 0, 0);
            __builtin_amdgcn_s_setprio(0);
            u16x4 pk0, pk1;
            float ls0 = 0.f, ls1 = 0.f;
            #pragma unroll
            for (int r = 0; r < 4; r++) {
                const float p0 = __expf(fmaf(s0[r], SCALEc, g0[r]) - SHIFTc);
                const float p1 = __expf(fmaf(s1[r], SCALEc, g1[r]) - SHIFTc);
                ls0 += p0; ls1 += p1;
                pk0[r] = f2bf(p0); pk1[r] = f2bf(p1);
            }
            lsum0 += ls0; lsum1 += ls1;
            *reinterpret_cast<u16x4*>(pl + l16 * LSTRIDE + ms * 16 + quad * 4) = pk0;
            *reinterpret_cast<u16x4*>(pl + (16 + l16) * LSTRIDE + ms * 16 + quad * 4) = pk1;
            if (ms < 7) { kb0 = nk0; kb1 = nk1; g0 = ng0; g1 = ng1; }
        }
        // --- PV: each V fragment feeds both n-subtiles ---
        const u16* vb0 = Vh + (size_t)l16 * Mn + m0 + quad * 8;
        #pragma unroll
        for (int kh = 0; kh < 4; kh++) {
            const bf16x8 pa0 = ld8bf(pl + l16 * LSTRIDE + kh * 32 + quad * 8);
            const bf16x8 pa1 = ld8bf(pl + (16 + l16) * LSTRIDE + kh * 32 + quad * 8);
            bf16x8 vb[4];
            #pragma unroll
            for (int ds = 0; ds < 4; ds++)
                vb[ds] = ld8bf(vb0 + (size_t)(ds * 16) * Mn + kh * 32);
            __builtin_amdgcn_s_setprio(1);
            #pragma unroll
            for (int ds = 0; ds < 4; ds++) {
                oacc[0][ds] = __builtin_amdgcn_mfma_f32_16x16x32_bf16(pa0, vb[ds], oacc[0][ds], 0, 0, 0);
                oacc[1][ds] = __builtin_amdgcn_mfma_f32_16x16x32_bf16(pa1, vb[ds], oacc[1][ds], 0, 0, 0);
            }
            __builtin_amdgcn_s_setprio(0);
        }
    }

    // reduce lsum across quads: all lanes end with full sum for col n=l16
    lsum0 += __shfl_xor(lsum0, 16);
    lsum0 += __shfl_xor(lsum0, 32);
    lsum1 += __shfl_xor(lsum1, 16);
    lsum1 += __shfl_xor(lsum1, 32);

    // write numerator partial (AO layout, per-split slab) and lsum partials
    float* PN = Pnum + (size_t)split * (Bn * (size_t)Nn * DIMn)
                     + ((size_t)b * Nn + nbase) * DIMn + h * Dn;
    #pragma unroll
    for (int nt = 0; nt < 2; nt++)
        #pragma unroll
        for (int r = 0; r < 4; r++)
            #pragma unroll
            for (int ds = 0; ds < 4; ds++)
                PN[(size_t)(nt * 16 + quad * 4 + r) * DIMn + ds * 16 + l16] = oacc[nt][ds][r];

    if (lane < 16) {
        Lsum[(((size_t)split * Bn + b) * Hn + h) * Nn + nbase + l16] = lsum0;
        Lsum[(((size_t)split * Bn + b) * Hn + h) * Nn + nbase + 16 + l16] = lsum1;
    }
}

// ---------------------------------------------------------------------------
// Combine: AO = sum_s Pnum[s] / sum_s Lsum[s]  -> bf16 (B*N, 256)
// One thread per 8 consecutive columns.
// ---------------------------------------------------------------------------
__global__ __launch_bounds__(256) void combine_kernel(
    const float* __restrict__ Pnum, const float* __restrict__ Lsum,
    u16* __restrict__ AO, int S)
{
    const int idx = blockIdx.x * 256 + threadIdx.x;    // [0, B*N*32)
    const int row = idx >> 5;                          // b*Nn + n
    const int c0  = (idx & 31) * 8;
    const int b = row >> 11, n = row & 2047, h = c0 >> 6;

    float l = 0.f;
    for (int s = 0; s < S; s++)
        l += Lsum[(((size_t)s * Bn + b) * Hn + h) * Nn + n];
    const float inv = 1.0f / l;

    f32x4 a0 = {}, a1 = {};
    for (int s = 0; s < S; s++) {
        const float* p = Pnum + (size_t)s * (Bn * (size_t)Nn * DIMn) + (size_t)row * DIMn + c0;
        a0 += *reinterpret_cast<const f32x4_a*>(p);
        a1 += *reinterpret_cast<const f32x4_a*>(p + 4);
    }
    u16x8 o;
    #pragma unroll
    for (int j = 0; j < 4; j++) {
        o[j]     = f2bf(a0[j] * inv);
        o[4 + j] = f2bf(a1[j] * inv);
    }
    *reinterpret_cast<u16x8*>(AO + (size_t)row * DIMn + c0) = o;
}

// ---------------------------------------------------------------------------
// Output projection: out = AO @ Wo^T + bo -> fp32 (B*N, 256), 16-row tiles
// ---------------------------------------------------------------------------
__global__ __launch_bounds__(256, 4) void oproj_kernel(
    const u16* __restrict__ A, const float* __restrict__ W,
    const float* __restrict__ bias, float* __restrict__ out)
{
    const int row0 = blockIdx.x * 16;
    const int wave = threadIdx.x >> 6, lane = threadIdx.x & 63;
    const int quad = lane >> 4, l16 = lane & 15;
    const int o0 = wave * 64;

    f32x4 acc[4] = {};
    #pragma unroll
    for (int k0 = 0; k0 < 256; k0 += 32) {
        bf16x8 wf[4];
        const bf16x8 af = ld8bf(A + (size_t)(row0 + l16) * DIMn + k0 + quad * 8);
        #pragma unroll
        for (int os = 0; os < 4; os++)
            wf[os] = ld8f_bf(W + (size_t)(o0 + os * 16 + l16) * DIMn + k0 + quad * 8);
        #pragma unroll
        for (int os = 0; os < 4; os++)
            acc[os] = __builtin_amdgcn_mfma_f32_16x16x32_bf16(af, wf[os], acc[os], 0, 0, 0);
    }
    #pragma unroll
    for (int os = 0; os < 4; os++) {
        const int col = o0 + os * 16 + l16;
        const float bb = bias[col];
        #pragma unroll
        for (int r = 0; r < 4; r++) {
            const int row = row0 + quad * 4 + r;
            out[(size_t)row * DIMn + col] = acc[os][r] + bb;
        }
    }
}

// ---------------------------------------------------------------------------
extern "C" void kernel_launch(void* const* d_in, const int* in_sizes, int n_in,
                              void* d_out, int out_size, void* d_ws, size_t ws_size,
                              hipStream_t stream) {
    const float* xq  = (const float*)d_in[0];
    const float* xc  = (const float*)d_in[1];
    const float* geo = (const float*)d_in[2];
    const float* Wq  = (const float*)d_in[3];
    const float* bq  = (const float*)d_in[4];
    const float* Wk  = (const float*)d_in[5];
    const float* bk  = (const float*)d_in[6];
    const float* Wv  = (const float*)d_in[7];
    const float* bv  = (const float*)d_in[8];
    const float* Wo  = (const float*)d_in[9];
    const float* bo  = (const float*)d_in[10];

    const int S = (ws_size >= (60ull << 20)) ? 4 : 1;

    char* ws = (char*)d_ws;
    float* Qw   = (float*)ws;                              // 8 MB fp32 (B,H,N,D)
    u16*   Kw   = (u16*)(ws + (8ull << 20));               // 4 MB bf16 (B,H,M,D)
    u16*   Vw   = (u16*)(ws + (12ull << 20));              // 4 MB bf16 (B,H,D,M)
    u16*   AOw  = (u16*)(ws + (16ull << 20));              // 4 MB bf16 (B*N, 256)
    float* Pnum = (float*)(ws + (20ull << 20));            // S x 8 MB fp32
    float* Lsum = (float*)(ws + (20ull << 20) + (size_t)S * (8ull << 20));  // S x 128 KB

    qkv_kernel<<<1024, 256, 0, stream>>>(xq, Wq, bq, xc, Wk, bk, Wv, bv, Qw, Kw, Vw);
    attn_kernel<<<dim3(Nn / 128, Hn, Bn * S), 256, 0, stream>>>(Qw, Kw, Vw, geo, Pnum, Lsum, S);
    combine_kernel<<<(Bn * Nn * 32) / 256, 256, 0, stream>>>(Pnum, Lsum, AOw, S);
    oproj_kernel<<<Bn * Nn / 16, 256, 0, stream>>>(AOw, Wo, bo, (float*)d_out);
}

// Round 2
// 561.325 us; speedup vs baseline: 1.0144x; 1.0144x over previous
//
#include <hip/hip_runtime.h>

typedef unsigned short u16;
typedef unsigned int u32;
using bf16x8  = __attribute__((ext_vector_type(8))) __bf16;
using u16x8   = __attribute__((ext_vector_type(8), may_alias)) u16;
using u16x4   = __attribute__((ext_vector_type(4), may_alias)) u16;
using f32x4   = __attribute__((ext_vector_type(4))) float;
using f32x4_a = __attribute__((ext_vector_type(4), may_alias)) float;

#define DEV __device__ __forceinline__

constexpr int Bn = 4, Hn = 4, Nn = 2048, Mn = 2048, Dn = 64, DIMn = 256;
constexpr float SCALEc = 0.125f;   // 64^-0.5
constexpr float SHIFTc = 12.0f;    // fixed softmax shift (max logit ~6; overflow needs >100)
constexpr int LSTRIDE = 152;       // u16; 76 dwords, 76%32=12 -> conflict-free b64/b128

DEV float bf2f(u16 h) { u32 u = ((u32)h) << 16; return __builtin_bit_cast(float, u); }
DEV u16 f2bf(float f) {
    u32 u = __builtin_bit_cast(u32, f);
    u += 0x7fffu + ((u >> 16) & 1u);   // RNE
    return (u16)(u >> 16);
}
DEV bf16x8 ld8bf(const u16* p) {
    return __builtin_bit_cast(bf16x8, *reinterpret_cast<const u16x8*>(p));
}
DEV bf16x8 ld8f_bf(const float* p) {
    const f32x4 a = *reinterpret_cast<const f32x4_a*>(p);
    const f32x4 b = *reinterpret_cast<const f32x4_a*>(p + 4);
    u16x8 r;
    r[0] = f2bf(a[0]); r[1] = f2bf(a[1]); r[2] = f2bf(a[2]); r[3] = f2bf(a[3]);
    r[4] = f2bf(b[0]); r[5] = f2bf(b[1]); r[6] = f2bf(b[2]); r[7] = f2bf(b[3]);
    return __builtin_bit_cast(bf16x8, r);
}

// ---------------------------------------------------------------------------
// Fused QKV projection (one launch, 1024 blocks, 16-row tiles):
//  blocks [0,512):   Q = x_query @ Wq^T + bq  -> fp32 (B,H,N,D)
//  blocks [512,1024): K -> bf16 (B,H,M,D); V -> bf16 (B,H,D,M) transposed
// ---------------------------------------------------------------------------
__global__ __launch_bounds__(256, 4) void qkv_kernel(
    const float* __restrict__ Xq, const float* __restrict__ Wq, const float* __restrict__ bq,
    const float* __restrict__ Xc, const float* __restrict__ Wk, const float* __restrict__ bk,
    const float* __restrict__ Wv, const float* __restrict__ bv,
    float* __restrict__ Q, u16* __restrict__ K, u16* __restrict__ V)
{
    const int wave = threadIdx.x >> 6, lane = threadIdx.x & 63;
    const int quad = lane >> 4, l16 = lane & 15;
    const int o0 = wave * 64;

    if (blockIdx.x < 512) {
        const int row0 = blockIdx.x * 16;
        const int b = row0 >> 11, n0 = row0 & 2047;
        f32x4 acc[4] = {};
        #pragma unroll
        for (int k0 = 0; k0 < 256; k0 += 32) {
            bf16x8 wf[4];
            const bf16x8 af = ld8f_bf(Xq + (size_t)(row0 + l16) * DIMn + k0 + quad * 8);
            #pragma unroll
            for (int os = 0; os < 4; os++)
                wf[os] = ld8f_bf(Wq + (size_t)(o0 + os * 16 + l16) * DIMn + k0 + quad * 8);
            #pragma unroll
            for (int os = 0; os < 4; os++)
                acc[os] = __builtin_amdgcn_mfma_f32_16x16x32_bf16(af, wf[os], acc[os], 0, 0, 0);
        }
        #pragma unroll
        for (int os = 0; os < 4; os++) {
            const int col = o0 + os * 16 + l16;
            const int h = col >> 6, d = col & 63;
            const float bb = bq[col];
            #pragma unroll
            for (int r = 0; r < 4; r++) {
                const int n = n0 + quad * 4 + r;
                Q[((size_t)(b * Hn + h) * Nn + n) * Dn + d] = acc[os][r] + bb;
            }
        }
    } else {
        const int row0 = (blockIdx.x - 512) * 16;
        const int b = row0 >> 11, n0 = row0 & 2047;
        f32x4 ack[4] = {};
        f32x4 acv[4] = {};
        #pragma unroll
        for (int k0 = 0; k0 < 256; k0 += 32) {
            bf16x8 wkf[4], wvf[4];
            const bf16x8 af = ld8f_bf(Xc + (size_t)(row0 + l16) * DIMn + k0 + quad * 8);
            #pragma unroll
            for (int os = 0; os < 4; os++) {
                wkf[os] = ld8f_bf(Wk + (size_t)(o0 + os * 16 + l16) * DIMn + k0 + quad * 8);
                wvf[os] = ld8f_bf(Wv + (size_t)(o0 + os * 16 + l16) * DIMn + k0 + quad * 8);
            }
            #pragma unroll
            for (int os = 0; os < 4; os++) {
                ack[os] = __builtin_amdgcn_mfma_f32_16x16x32_bf16(af, wkf[os], ack[os], 0, 0, 0);
                acv[os] = __builtin_amdgcn_mfma_f32_16x16x32_bf16(wvf[os], af, acv[os], 0, 0, 0);
            }
        }
        #pragma unroll
        for (int os = 0; os < 4; os++) {
            const int col = o0 + os * 16 + l16;
            const int h = col >> 6, d = col & 63;
            const float bb = bk[col];
            #pragma unroll
            for (int r = 0; r < 4; r++) {
                const int m = n0 + quad * 4 + r;
                K[((size_t)(b * Hn + h) * Mn + m) * Dn + d] = f2bf(ack[os][r] + bb);
            }
        }
        #pragma unroll
        for (int os = 0; os < 4; os++)
            #pragma unroll
            for (int r = 0; r < 4; r++) {
                const int colf = o0 + os * 16 + quad * 4 + r;
                const int h = colf >> 6, d = colf & 63;
                const float bb = bv[colf];
                const int m = n0 + l16;
                V[((size_t)(b * Hn + h) * Dn + d) * Mn + m] = f2bf(acv[os][r] + bb);
            }
    }
}

// ---------------------------------------------------------------------------
// Flash attention, split-M, transposed score tiles (S^T = K Q^T).
// Grid (N/64, H, B*S). Block 256 thr = 4 waves; wave owns 16 Q-rows and
// M-range [split*mlen, (split+1)*mlen).
// Latency hiding: geo for the whole 128-m tile is batch-loaded (8 f32x4 in
// flight) and refilled for the NEXT tile at the start of the PV phase (PV's
// V-loads + MFMAs cover the ~900cy HBM latency). K fragments are depth-1
// prefetched, chained across tiles (prefetch at ms==7 targets next tile).
// Fixed softmax shift -> split partials directly addable; oproj normalizes.
// Single-buffer wave-private LDS (in-order DS pipe), stride 152 -> no
// conflicts. No barriers. Register budget ~116 incl. AGPR -> fits
// __launch_bounds__(256,4) without spills (round-1 spilled at 32 rows/wave).
// ---------------------------------------------------------------------------
__global__ __launch_bounds__(256, 4) void attn_kernel(
    const float* __restrict__ Q,    // (B,H,N,D) fp32
    const u16* __restrict__ K,      // (B,H,M,D) bf16
    const u16* __restrict__ V,      // (B,H,D,M) bf16
    const float* __restrict__ geo,  // (B,H,N,M) fp32
    float* __restrict__ Pnum,       // (S, B*N, 256) fp32 numerator partials
    float* __restrict__ Lsum,       // (S, B, H, N) fp32 denominator partials
    int S)
{
    __shared__ __align__(16) u16 lds[4][16 * LSTRIDE];   // 19456 B

    const int h = blockIdx.y;
    const int b = blockIdx.z / S, split = blockIdx.z % S;
    const int wave = threadIdx.x >> 6, lane = threadIdx.x & 63;
    const int quad = lane >> 4, l16 = lane & 15;
    const int nbase = blockIdx.x * 64 + wave * 16;
    const int mlen = Mn / S, mbeg = split * mlen, mend = mbeg + mlen;

    const float* Qh = Q + ((size_t)(b * Hn + h) * Nn + nbase) * Dn;
    const u16*   Kh = K + (size_t)(b * Hn + h) * Mn * Dn;
    const u16*   Vh = V + (size_t)(b * Hn + h) * Dn * Mn;
    const float* Gl = geo + ((size_t)(b * Hn + h) * Nn + nbase + l16) * (size_t)Mn + quad * 4;

    // Q^T B-fragments (hi/lo split for compensated QK^T)
    bf16x8 qh[2], ql[2];
    #pragma unroll
    for (int kh = 0; kh < 2; kh++) {
        const float* qp = Qh + (size_t)l16 * Dn + kh * 32 + quad * 8;
        const f32x4 a = *reinterpret_cast<const f32x4_a*>(qp);
        const f32x4 c = *reinterpret_cast<const f32x4_a*>(qp + 4);
        u16x8 hi, lo;
        #pragma unroll
        for (int j = 0; j < 4; j++) {
            hi[j] = f2bf(a[j]); lo[j] = f2bf(a[j] - bf2f(hi[j]));
            hi[4 + j] = f2bf(c[j]); lo[4 + j] = f2bf(c[j] - bf2f(hi[4 + j]));
        }
        qh[kh] = __builtin_bit_cast(bf16x8, hi);
        ql[kh] = __builtin_bit_cast(bf16x8, lo);
    }

    f32x4 oacc[4] = {};
    float lsum = 0.f;
    u16* pl = &lds[wave][0];
    const u16* kbase = Kh + (size_t)l16 * Dn + quad * 8;
    const u16* vbase = Vh + (size_t)l16 * Mn + quad * 8;

    // prologue: batch-load geo for first tile + first K fragment pair
    f32x4 g[8];
    #pragma unroll
    for (int ms = 0; ms < 8; ms++)
        g[ms] = *reinterpret_cast<const f32x4_a*>(Gl + mbeg + ms * 16);
    bf16x8 kb0 = ld8bf(kbase + (size_t)mbeg * Dn);
    bf16x8 kb1 = ld8bf(kbase + (size_t)mbeg * Dn + 32);

    for (int m0 = mbeg; m0 < mend; m0 += 128) {
        // --- QK^T + softmax numerator for 16n x 128m ---
        #pragma unroll
        for (int ms = 0; ms < 8; ms++) {
            int mb = m0 + (ms + 1) * 16;            // ms==7 -> next tile's ms=0
            if (mb > mend - 16) mb = mend - 16;     // clamp (uniform, L2-hit reload)
            const u16* kp = kbase + (size_t)mb * Dn;
            const bf16x8 nk0 = ld8bf(kp);
            const bf16x8 nk1 = ld8bf(kp + 32);
            f32x4 s = {};
            __builtin_amdgcn_s_setprio(1);
            s = __builtin_amdgcn_mfma_f32_16x16x32_bf16(kb0, qh[0], s, 0, 0, 0);
            s = __builtin_amdgcn_mfma_f32_16x16x32_bf16(kb0, ql[0], s, 0, 0, 0);
            s = __builtin_amdgcn_mfma_f32_16x16x32_bf16(kb1, qh[1], s, 0, 0, 0);
            s = __builtin_amdgcn_mfma_f32_16x16x32_bf16(kb1, ql[1], s, 0, 0, 0);
            __builtin_amdgcn_s_setprio(0);
            u16x4 pk;
            float ls = 0.f;
            #pragma unroll
            for (int r = 0; r < 4; r++) {
                const float p = __expf(fmaf(s[r], SCALEc, g[ms][r]) - SHIFTc);
                ls += p;
                pk[r] = f2bf(p);
            }
            lsum += ls;
            *reinterpret_cast<u16x4*>(pl + l16 * LSTRIDE + ms * 16 + quad * 4) = pk;
            kb0 = nk0; kb1 = nk1;
        }
        // refill geo batch for NEXT tile; latency hides under the PV phase
        if (m0 + 128 < mend) {
            #pragma unroll
            for (int ms = 0; ms < 8; ms++)
                g[ms] = *reinterpret_cast<const f32x4_a*>(Gl + m0 + 128 + ms * 16);
        }
        // --- PV ---
        #pragma unroll
        for (int kh = 0; kh < 4; kh++) {
            const bf16x8 pa = ld8bf(pl + l16 * LSTRIDE + kh * 32 + quad * 8);
            bf16x8 vb[4];
            #pragma unroll
            for (int ds = 0; ds < 4; ds++)
                vb[ds] = ld8bf(vbase + (size_t)(ds * 16) * Mn + m0 + kh * 32);
            __builtin_amdgcn_s_setprio(1);
            #pragma unroll
            for (int ds = 0; ds < 4; ds++)
                oacc[ds] = __builtin_amdgcn_mfma_f32_16x16x32_bf16(pa, vb[ds], oacc[ds], 0, 0, 0);
            __builtin_amdgcn_s_setprio(0);
        }
    }

    // reduce lsum across quads: all lanes end with full sum for col n=l16
    lsum += __shfl_xor(lsum, 16);
    lsum += __shfl_xor(lsum, 32);

    // write numerator partial (AO layout, per-split slab) and lsum partial
    float* PN = Pnum + (size_t)split * (Bn * (size_t)Nn * DIMn)
                     + ((size_t)b * Nn + nbase) * DIMn + h * Dn;
    #pragma unroll
    for (int r = 0; r < 4; r++)
        #pragma unroll
        for (int ds = 0; ds < 4; ds++)
            PN[(size_t)(quad * 4 + r) * DIMn + ds * 16 + l16] = oacc[ds][r];

    if (lane < 16)
        Lsum[(((size_t)split * Bn + b) * Hn + h) * Nn + nbase + l16] = lsum;
}

// ---------------------------------------------------------------------------
// Fused combine + output projection:
// AO[row][col] = (sum_s Pnum[s][row][col]) / (sum_s Lsum[s][h(col)][row-part])
// out = AO @ Wo^T + bo -> fp32 (B*N, 256), 16-row tiles, 512 blocks.
// Normalization happens in-register right before the bf16 MFMA A-fragment,
// eliminating the separate combine kernel (+1 launch, 8 MB traffic).
// ---------------------------------------------------------------------------
__global__ __launch_bounds__(256, 4) void oproj_kernel(
    const float* __restrict__ Pnum, const float* __restrict__ Lsum,
    const float* __restrict__ W, const float* __restrict__ bias,
    float* __restrict__ out, int S)
{
    const int row0 = blockIdx.x * 16;
    const int wave = threadIdx.x >> 6, lane = threadIdx.x & 63;
    const int quad = lane >> 4, l16 = lane & 15;
    const int o0 = wave * 64;
    const size_t slab = (size_t)Bn * Nn * DIMn;

    // lane l16 owns A-row (row0+l16); denominators per head for that row
    const int arow = row0 + l16;
    const int b = arow >> 11, n = arow & 2047;
    float inv[4];
    #pragma unroll
    for (int hh = 0; hh < 4; hh++) {
        float l = 0.f;
        for (int s = 0; s < S; s++)
            l += Lsum[(((size_t)s * Bn + b) * Hn + hh) * Nn + n];
        inv[hh] = 1.0f / l;
    }

    f32x4 acc[4] = {};
    #pragma unroll
    for (int k0 = 0; k0 < 256; k0 += 32) {
        bf16x8 wf[4];
        #pragma unroll
        for (int os = 0; os < 4; os++)
            wf[os] = ld8f_bf(W + (size_t)(o0 + os * 16 + l16) * DIMn + k0 + quad * 8);
        // combine Pnum slabs -> normalized bf16 A-fragment
        f32x4 a0 = {}, a1 = {};
        for (int s = 0; s < S; s++) {
            const float* p = Pnum + (size_t)s * slab + (size_t)arow * DIMn + k0 + quad * 8;
            a0 += *reinterpret_cast<const f32x4_a*>(p);
            a1 += *reinterpret_cast<const f32x4_a*>(p + 4);
        }
        const float iv = inv[(k0 + quad * 8) >> 6];
        u16x8 r;
        #pragma unroll
        for (int j = 0; j < 4; j++) {
            r[j]     = f2bf(a0[j] * iv);
            r[4 + j] = f2bf(a1[j] * iv);
        }
        const bf16x8 af = __builtin_bit_cast(bf16x8, r);
        #pragma unroll
        for (int os = 0; os < 4; os++)
            acc[os] = __builtin_amdgcn_mfma_f32_16x16x32_bf16(af, wf[os], acc[os], 0, 0, 0);
    }
    #pragma unroll
    for (int os = 0; os < 4; os++) {
        const int col = o0 + os * 16 + l16;
        const float bb = bias[col];
        #pragma unroll
        for (int r = 0; r < 4; r++) {
            const int row = row0 + quad * 4 + r;
            out[(size_t)row * DIMn + col] = acc[os][r] + bb;
        }
    }
}

// ---------------------------------------------------------------------------
extern "C" void kernel_launch(void* const* d_in, const int* in_sizes, int n_in,
                              void* d_out, int out_size, void* d_ws, size_t ws_size,
                              hipStream_t stream) {
    const float* xq  = (const float*)d_in[0];
    const float* xc  = (const float*)d_in[1];
    const float* geo = (const float*)d_in[2];
    const float* Wq  = (const float*)d_in[3];
    const float* bq  = (const float*)d_in[4];
    const float* Wk  = (const float*)d_in[5];
    const float* bk  = (const float*)d_in[6];
    const float* Wv  = (const float*)d_in[7];
    const float* bv  = (const float*)d_in[8];
    const float* Wo  = (const float*)d_in[9];
    const float* bo  = (const float*)d_in[10];

    const int S = (ws_size >= (60ull << 20)) ? 4 : 1;

    char* ws = (char*)d_ws;
    float* Qw   = (float*)ws;                              // 8 MB fp32 (B,H,N,D)
    u16*   Kw   = (u16*)(ws + (8ull << 20));               // 4 MB bf16 (B,H,M,D)
    u16*   Vw   = (u16*)(ws + (12ull << 20));              // 4 MB bf16 (B,H,D,M)
    float* Pnum = (float*)(ws + (20ull << 20));            // S x 8 MB fp32
    float* Lsum = (float*)(ws + (20ull << 20) + (size_t)S * (8ull << 20));  // S x 128 KB

    qkv_kernel<<<1024, 256, 0, stream>>>(xq, Wq, bq, xc, Wk, bk, Wv, bv, Qw, Kw, Vw);
    attn_kernel<<<dim3(Nn / 64, Hn, Bn * S), 256, 0, stream>>>(Qw, Kw, Vw, geo, Pnum, Lsum, S);
    oproj_kernel<<<Bn * Nn / 16, 256, 0, stream>>>(Pnum, Lsum, Wo, bo, (float*)d_out, S);
}

// Round 3
// 553.823 us; speedup vs baseline: 1.0282x; 1.0135x over previous
//
#include <hip/hip_runtime.h>

typedef unsigned short u16;
typedef unsigned int u32;
using bf16x8  = __attribute__((ext_vector_type(8))) __bf16;
using u16x8   = __attribute__((ext_vector_type(8), may_alias)) u16;
using u16x4   = __attribute__((ext_vector_type(4), may_alias)) u16;
using f32x4   = __attribute__((ext_vector_type(4))) float;
using f32x4_a = __attribute__((ext_vector_type(4), may_alias)) float;

#define DEV __device__ __forceinline__

constexpr int Bn = 4, Hn = 4, Nn = 2048, Mn = 2048, Dn = 64, DIMn = 256;
constexpr float SCALEc = 0.125f;   // 64^-0.5
constexpr float SHIFTc = 12.0f;    // fixed softmax shift (max logit ~6; overflow needs >100)
constexpr int LSTRIDE = 152;       // u16; 76 dwords, 76%32=12 -> conflict-free b64/b128

DEV float bf2f(u16 h) { u32 u = ((u32)h) << 16; return __builtin_bit_cast(float, u); }
DEV u16 f2bf(float f) {
    u32 u = __builtin_bit_cast(u32, f);
    u += 0x7fffu + ((u >> 16) & 1u);   // RNE
    return (u16)(u >> 16);
}
DEV bf16x8 ld8bf(const u16* p) {
    return __builtin_bit_cast(bf16x8, *reinterpret_cast<const u16x8*>(p));
}
DEV bf16x8 ld8f_bf(const float* p) {
    const f32x4 a = *reinterpret_cast<const f32x4_a*>(p);
    const f32x4 b = *reinterpret_cast<const f32x4_a*>(p + 4);
    u16x8 r;
    r[0] = f2bf(a[0]); r[1] = f2bf(a[1]); r[2] = f2bf(a[2]); r[3] = f2bf(a[3]);
    r[4] = f2bf(b[0]); r[5] = f2bf(b[1]); r[6] = f2bf(b[2]); r[7] = f2bf(b[3]);
    return __builtin_bit_cast(bf16x8, r);
}

// async global->LDS DMA, 16B per lane; dest = wave-uniform base + lane*16
typedef __attribute__((address_space(1))) const unsigned int as1_uint;
typedef __attribute__((address_space(3))) unsigned int as3_uint;
DEV void dma16(const float* g, float* l) {
    __builtin_amdgcn_global_load_lds((as1_uint*)g, (as3_uint*)l, 16, 0, 0);
}

// ---------------------------------------------------------------------------
// Fused QKV projection (one launch, 1024 blocks, 16-row tiles):
//  blocks [0,512):   Q = x_query @ Wq^T + bq  -> fp32 (B,H,N,D)
//  blocks [512,1024): K -> bf16 (B,H,M,D); V -> bf16 (B,H,D,M) transposed
// Short fragment live-ranges (load right before MFMA) to fit the 64-VGPR
// cap the allocator applies at zero-LDS/8-wave occupancy.
// ---------------------------------------------------------------------------
__global__ __launch_bounds__(256) void qkv_kernel(
    const float* __restrict__ Xq, const float* __restrict__ Wq, const float* __restrict__ bq,
    const float* __restrict__ Xc, const float* __restrict__ Wk, const float* __restrict__ bk,
    const float* __restrict__ Wv, const float* __restrict__ bv,
    float* __restrict__ Q, u16* __restrict__ K, u16* __restrict__ V)
{
    const int wave = threadIdx.x >> 6, lane = threadIdx.x & 63;
    const int quad = lane >> 4, l16 = lane & 15;
    const int o0 = wave * 64;

    if (blockIdx.x < 512) {
        const int row0 = blockIdx.x * 16;
        const int b = row0 >> 11, n0 = row0 & 2047;
        f32x4 acc[4] = {};
        #pragma unroll
        for (int k0 = 0; k0 < 256; k0 += 32) {
            const bf16x8 af = ld8f_bf(Xq + (size_t)(row0 + l16) * DIMn + k0 + quad * 8);
            #pragma unroll
            for (int os = 0; os < 4; os++) {
                const bf16x8 wf = ld8f_bf(Wq + (size_t)(o0 + os * 16 + l16) * DIMn + k0 + quad * 8);
                acc[os] = __builtin_amdgcn_mfma_f32_16x16x32_bf16(af, wf, acc[os], 0, 0, 0);
            }
        }
        #pragma unroll
        for (int os = 0; os < 4; os++) {
            const int col = o0 + os * 16 + l16;
            const int h = col >> 6, d = col & 63;
            const float bb = bq[col];
            #pragma unroll
            for (int r = 0; r < 4; r++) {
                const int n = n0 + quad * 4 + r;
                Q[((size_t)(b * Hn + h) * Nn + n) * Dn + d] = acc[os][r] + bb;
            }
        }
    } else {
        const int row0 = (blockIdx.x - 512) * 16;
        const int b = row0 >> 11, n0 = row0 & 2047;
        f32x4 ack[4] = {};
        f32x4 acv[4] = {};
        #pragma unroll
        for (int k0 = 0; k0 < 256; k0 += 32) {
            const bf16x8 af = ld8f_bf(Xc + (size_t)(row0 + l16) * DIMn + k0 + quad * 8);
            #pragma unroll
            for (int os = 0; os < 4; os++) {
                const bf16x8 wkf = ld8f_bf(Wk + (size_t)(o0 + os * 16 + l16) * DIMn + k0 + quad * 8);
                ack[os] = __builtin_amdgcn_mfma_f32_16x16x32_bf16(af, wkf, ack[os], 0, 0, 0);
                const bf16x8 wvf = ld8f_bf(Wv + (size_t)(o0 + os * 16 + l16) * DIMn + k0 + quad * 8);
                acv[os] = __builtin_amdgcn_mfma_f32_16x16x32_bf16(wvf, af, acv[os], 0, 0, 0);
            }
        }
        #pragma unroll
        for (int os = 0; os < 4; os++) {
            const int col = o0 + os * 16 + l16;
            const int h = col >> 6, d = col & 63;
            const float bb = bk[col];
            #pragma unroll
            for (int r = 0; r < 4; r++) {
                const int m = n0 + quad * 4 + r;
                K[((size_t)(b * Hn + h) * Mn + m) * Dn + d] = f2bf(ack[os][r] + bb);
            }
        }
        #pragma unroll
        for (int os = 0; os < 4; os++)
            #pragma unroll
            for (int r = 0; r < 4; r++) {
                const int colf = o0 + os * 16 + quad * 4 + r;
                const int h = colf >> 6, d = colf & 63;
                const float bb = bv[colf];
                const int m = n0 + l16;
                V[((size_t)(b * Hn + h) * Dn + d) * Mn + m] = f2bf(acv[os][r] + bb);
            }
    }
}

// ---------------------------------------------------------------------------
// Flash attention, split-M, transposed score tiles (S^T = K Q^T).
// Grid (N/64, H, B*S). Block 256 thr = 4 waves; wave owns 16 Q-rows.
// Latency hiding WITHOUT register pressure:
//  - geo staged per-tile into wave-private LDS via global_load_lds DMA
//    (zero VGPRs in flight; issued for tile t+1 right before PV of tile t,
//    whose V-loads + MFMAs cover the HBM latency; vmcnt(0) at tile top).
//  - K fragments depth-1 register prefetch, chained across tiles.
//  - V fragments depth-1 register prefetch inside the PV phase.
// LDS 52224 B/block -> 3 blocks/CU -> allocator VGPR cap ~168: the ~100-reg
// prefetch state fits with NO spills (rounds 1-2 spilled at the 64-reg cap
// implied by 19456 B LDS). Wave-private buffers, no barriers.
// Fixed softmax shift -> split partials directly addable; oproj normalizes.
// ---------------------------------------------------------------------------
__global__ __launch_bounds__(256) void attn_kernel(
    const float* __restrict__ Q,    // (B,H,N,D) fp32
    const u16* __restrict__ K,      // (B,H,M,D) bf16
    const u16* __restrict__ V,      // (B,H,D,M) bf16
    const float* __restrict__ geo,  // (B,H,N,M) fp32
    float* __restrict__ Pnum,       // (S, B*N, 256) fp32 numerator partials
    float* __restrict__ Lsum,       // (S, B, H, N) fp32 denominator partials
    int S)
{
    __shared__ __align__(16) u16 plds[4][16 * LSTRIDE];   // 19456 B: P tiles
    __shared__ __align__(16) float glds[4][8][256];       // 32768 B: geo tiles

    const int h = blockIdx.y;
    const int b = blockIdx.z / S, split = blockIdx.z % S;
    const int wave = threadIdx.x >> 6, lane = threadIdx.x & 63;
    const int quad = lane >> 4, l16 = lane & 15;
    const int nbase = blockIdx.x * 64 + wave * 16;
    const int mlen = Mn / S, mbeg = split * mlen, mend = mbeg + mlen;

    const float* Qh = Q + ((size_t)(b * Hn + h) * Nn + nbase) * Dn;
    const u16*   Kh = K + (size_t)(b * Hn + h) * Mn * Dn;
    const u16*   Vh = V + (size_t)(b * Hn + h) * Dn * Mn;
    // per-lane geo source: row (nbase+l16), 16B chunk at col quad*4 within
    // each 16-col ms-block -> DMA dest lane*16 matches exp read-back below.
    const float* Gl = geo + ((size_t)(b * Hn + h) * Nn + nbase + l16) * (size_t)Mn + quad * 4;

    // Q^T B-fragments (hi/lo split for compensated QK^T)
    bf16x8 qh[2], ql[2];
    #pragma unroll
    for (int kh = 0; kh < 2; kh++) {
        const float* qp = Qh + (size_t)l16 * Dn + kh * 32 + quad * 8;
        const f32x4 a = *reinterpret_cast<const f32x4_a*>(qp);
        const f32x4 c = *reinterpret_cast<const f32x4_a*>(qp + 4);
        u16x8 hi, lo;
        #pragma unroll
        for (int j = 0; j < 4; j++) {
            hi[j] = f2bf(a[j]); lo[j] = f2bf(a[j] - bf2f(hi[j]));
            hi[4 + j] = f2bf(c[j]); lo[4 + j] = f2bf(c[j] - bf2f(hi[4 + j]));
        }
        qh[kh] = __builtin_bit_cast(bf16x8, hi);
        ql[kh] = __builtin_bit_cast(bf16x8, lo);
    }

    f32x4 oacc[4] = {};
    float lsum = 0.f;
    u16* pl = &plds[wave][0];
    float* gw = &glds[wave][0][0];            // wave-private 8 KB geo buffer
    const float* gr = gw + lane * 4;          // this lane's 4 floats per ms-block
    const u16* kbase = Kh + (size_t)l16 * Dn + quad * 8;
    const u16* vbase = Vh + (size_t)l16 * Mn + quad * 8;

    // prologue: DMA geo tile 0; load first K fragment pair
    #pragma unroll
    for (int ms = 0; ms < 8; ms++)
        dma16(Gl + mbeg + ms * 16, gw + ms * 256);
    bf16x8 kb0 = ld8bf(kbase + (size_t)mbeg * Dn);
    bf16x8 kb1 = ld8bf(kbase + (size_t)mbeg * Dn + 32);

    for (int m0 = mbeg; m0 < mend; m0 += 128) {
        // geo DMA + K prefetch landed (everything older is consumed anyway)
        asm volatile("s_waitcnt vmcnt(0)" ::: "memory");
        // --- QK^T + softmax numerator for 16n x 128m ---
        #pragma unroll
        for (int ms = 0; ms < 8; ms++) {
            int mb = m0 + (ms + 1) * 16;            // ms==7 -> next tile's ms=0
            if (mb > mend - 16) mb = mend - 16;     // clamp (uniform, L2-hit reload)
            const u16* kp = kbase + (size_t)mb * Dn;
            const bf16x8 nk0 = ld8bf(kp);
            const bf16x8 nk1 = ld8bf(kp + 32);
            f32x4 s = {};
            __builtin_amdgcn_s_setprio(1);
            s = __builtin_amdgcn_mfma_f32_16x16x32_bf16(kb0, qh[0], s, 0, 0, 0);
            s = __builtin_amdgcn_mfma_f32_16x16x32_bf16(kb0, ql[0], s, 0, 0, 0);
            s = __builtin_amdgcn_mfma_f32_16x16x32_bf16(kb1, qh[1], s, 0, 0, 0);
            s = __builtin_amdgcn_mfma_f32_16x16x32_bf16(kb1, ql[1], s, 0, 0, 0);
            __builtin_amdgcn_s_setprio(0);
            const f32x4 g = *reinterpret_cast<const f32x4_a*>(gr + ms * 256);
            u16x4 pk;
            float ls = 0.f;
            #pragma unroll
            for (int r = 0; r < 4; r++) {
                const float p = __expf(fmaf(s[r], SCALEc, g[r]) - SHIFTc);
                ls += p;
                pk[r] = f2bf(p);
            }
            lsum += ls;
            *reinterpret_cast<u16x4*>(pl + l16 * LSTRIDE + ms * 16 + quad * 4) = pk;
            kb0 = nk0; kb1 = nk1;
        }
        // issue geo DMA for NEXT tile over the just-consumed buffer; the PV
        // phase below covers its latency. lgkmcnt(0): all geo ds_reads done.
        if (m0 + 128 < mend) {
            asm volatile("s_waitcnt lgkmcnt(0)" ::: "memory");
            #pragma unroll
            for (int ms = 0; ms < 8; ms++)
                dma16(Gl + (m0 + 128) + ms * 16, gw + ms * 256);
        }
        // --- PV with depth-1 V prefetch ---
        bf16x8 vcur[4], vnxt[4];
        #pragma unroll
        for (int ds = 0; ds < 4; ds++)
            vcur[ds] = ld8bf(vbase + (size_t)(ds * 16) * Mn + m0);
        #pragma unroll
        for (int kh = 0; kh < 4; kh++) {
            if (kh < 3) {
                #pragma unroll
                for (int ds = 0; ds < 4; ds++)
                    vnxt[ds] = ld8bf(vbase + (size_t)(ds * 16) * Mn + m0 + (kh + 1) * 32);
            }
            const bf16x8 pa = ld8bf(pl + l16 * LSTRIDE + kh * 32 + quad * 8);
            __builtin_amdgcn_s_setprio(1);
            #pragma unroll
            for (int ds = 0; ds < 4; ds++)
                oacc[ds] = __builtin_amdgcn_mfma_f32_16x16x32_bf16(pa, vcur[ds], oacc[ds], 0, 0, 0);
            __builtin_amdgcn_s_setprio(0);
            #pragma unroll
            for (int ds = 0; ds < 4; ds++) vcur[ds] = vnxt[ds];
        }
    }

    // reduce lsum across quads: all lanes end with full sum for col n=l16
    lsum += __shfl_xor(lsum, 16);
    lsum += __shfl_xor(lsum, 32);

    // write numerator partial (AO layout, per-split slab) and lsum partial
    float* PN = Pnum + (size_t)split * (Bn * (size_t)Nn * DIMn)
                     + ((size_t)b * Nn + nbase) * DIMn + h * Dn;
    #pragma unroll
    for (int r = 0; r < 4; r++)
        #pragma unroll
        for (int ds = 0; ds < 4; ds++)
            PN[(size_t)(quad * 4 + r) * DIMn + ds * 16 + l16] = oacc[ds][r];

    if (lane < 16)
        Lsum[(((size_t)split * Bn + b) * Hn + h) * Nn + nbase + l16] = lsum;
}

// ---------------------------------------------------------------------------
// Fused combine + output projection:
// AO[row][col] = (sum_s Pnum[s][row][col]) / (sum_s Lsum[s][h(col)][row-part])
// out = AO @ Wo^T + bo -> fp32 (B*N, 256), 16-row tiles, 512 blocks.
// Normalization happens in-register right before the bf16 MFMA A-fragment.
// ---------------------------------------------------------------------------
__global__ __launch_bounds__(256) void oproj_kernel(
    const float* __restrict__ Pnum, const float* __restrict__ Lsum,
    const float* __restrict__ W, const float* __restrict__ bias,
    float* __restrict__ out, int S)
{
    const int row0 = blockIdx.x * 16;
    const int wave = threadIdx.x >> 6, lane = threadIdx.x & 63;
    const int quad = lane >> 4, l16 = lane & 15;
    const int o0 = wave * 64;
    const size_t slab = (size_t)Bn * Nn * DIMn;

    // lane l16 owns A-row (row0+l16); denominators per head for that row
    const int arow = row0 + l16;
    const int b = arow >> 11, n = arow & 2047;
    float inv[4];
    #pragma unroll
    for (int hh = 0; hh < 4; hh++) {
        float l = 0.f;
        for (int s = 0; s < S; s++)
            l += Lsum[(((size_t)s * Bn + b) * Hn + hh) * Nn + n];
        inv[hh] = 1.0f / l;
    }

    f32x4 acc[4] = {};
    #pragma unroll
    for (int k0 = 0; k0 < 256; k0 += 32) {
        // combine Pnum slabs -> normalized bf16 A-fragment
        f32x4 a0 = {}, a1 = {};
        for (int s = 0; s < S; s++) {
            const float* p = Pnum + (size_t)s * slab + (size_t)arow * DIMn + k0 + quad * 8;
            a0 += *reinterpret_cast<const f32x4_a*>(p);
            a1 += *reinterpret_cast<const f32x4_a*>(p + 4);
        }
        const float iv = inv[(k0 + quad * 8) >> 6];
        u16x8 r;
        #pragma unroll
        for (int j = 0; j < 4; j++) {
            r[j]     = f2bf(a0[j] * iv);
            r[4 + j] = f2bf(a1[j] * iv);
        }
        const bf16x8 af = __builtin_bit_cast(bf16x8, r);
        #pragma unroll
        for (int os = 0; os < 4; os++) {
            const bf16x8 wf = ld8f_bf(W + (size_t)(o0 + os * 16 + l16) * DIMn + k0 + quad * 8);
            acc[os] = __builtin_amdgcn_mfma_f32_16x16x32_bf16(af, wf, acc[os], 0, 0, 0);
        }
    }
    #pragma unroll
    for (int os = 0; os < 4; os++) {
        const int col = o0 + os * 16 + l16;
        const float bb = bias[col];
        #pragma unroll
        for (int r = 0; r < 4; r++) {
            const int row = row0 + quad * 4 + r;
            out[(size_t)row * DIMn + col] = acc[os][r] + bb;
        }
    }
}

// ---------------------------------------------------------------------------
extern "C" void kernel_launch(void* const* d_in, const int* in_sizes, int n_in,
                              void* d_out, int out_size, void* d_ws, size_t ws_size,
                              hipStream_t stream) {
    const float* xq  = (const float*)d_in[0];
    const float* xc  = (const float*)d_in[1];
    const float* geo = (const float*)d_in[2];
    const float* Wq  = (const float*)d_in[3];
    const float* bq  = (const float*)d_in[4];
    const float* Wk  = (const float*)d_in[5];
    const float* bk  = (const float*)d_in[6];
    const float* Wv  = (const float*)d_in[7];
    const float* bv  = (const float*)d_in[8];
    const float* Wo  = (const float*)d_in[9];
    const float* bo  = (const float*)d_in[10];

    const int S = (ws_size >= (60ull << 20)) ? 4 : 1;

    char* ws = (char*)d_ws;
    float* Qw   = (float*)ws;                              // 8 MB fp32 (B,H,N,D)
    u16*   Kw   = (u16*)(ws + (8ull << 20));               // 4 MB bf16 (B,H,M,D)
    u16*   Vw   = (u16*)(ws + (12ull << 20));              // 4 MB bf16 (B,H,D,M)
    float* Pnum = (float*)(ws + (20ull << 20));            // S x 8 MB fp32
    float* Lsum = (float*)(ws + (20ull << 20) + (size_t)S * (8ull << 20));  // S x 128 KB

    qkv_kernel<<<1024, 256, 0, stream>>>(xq, Wq, bq, xc, Wk, bk, Wv, bv, Qw, Kw, Vw);
    attn_kernel<<<dim3(Nn / 64, Hn, Bn * S), 256, 0, stream>>>(Qw, Kw, Vw, geo, Pnum, Lsum, S);
    oproj_kernel<<<Bn * Nn / 16, 256, 0, stream>>>(Pnum, Lsum, Wo, bo, (float*)d_out, S);
}